// Round 13
// baseline (152.860 us; speedup 1.0000x reference)
//
#include <hip/hip_runtime.h>
#include <hip/hip_fp16.h>
#include <math.h>

// TSC (order-3) particle-to-mesh deposition.
//
// Fast path (C==8, n%4==0, n<=256): per-1x1-column capped bin lists of
// PACKED 32B records (pos 3xf32 + emb 8xf16), then WAVE-SCATTER-GATHER:
// lanes = (atom-slot, z-corner) pairs, 8 ds_add_f32 into the wave's PRIVATE
// LDS column [8ch][n], per-channel float4 streaming writeout.
// r13 changes vs r12 (~146us, three nulls in a row):
//  (1) hipMemsetAsync(counts) REMOVED from the timed path -- r12's profile
//      shows fillBufferAligned rows writing exactly our 156.281KB counts
//      buffer taking 145-147us at ~zero utilization. Replaced with our own
//      vectorized zero kernel (~3us).
//  (2) persistent-lite gather: 2500 blocks x 4 contiguous column-group
//      tiles each (amortizes any per-block fixed cost 4x; body unchanged,
//      wave-private, no cross-tile barriers needed).
//
// Fallbacks: interleaved-atomic two-phase (C==8), generic planar atomics.

#define KColCAP 16   // records per 1x1 column bin (lambda ~2.5)

typedef float nfloat4 __attribute__((ext_vector_type(4)));

__device__ __forceinline__ float tsc_w(int o, float d) {
    float t = 0.5f + (float)o * d;
    return (o == 0) ? (0.75f - d * d) : (0.5f * t * t);
}

__device__ __forceinline__ float inv_spacing(const float* __restrict__ cell, int n) {
    float tr = cell[0] + cell[4] + cell[8];
    return (3.0f * (float)n) / tr;
}

__device__ __forceinline__ float2 unpack_h2(float bits) {
    unsigned int u = __float_as_uint(bits);
    __half2 h = *(__half2*)&u;
    return __half22float2(h);
}

// ---------------- zero kernel (replaces hipMemsetAsync in timed path) ----------------

__global__ __launch_bounds__(256) void zero_ints(int* __restrict__ p, int nwords)
{
    int i = blockIdx.x * blockDim.x + threadIdx.x;
    int stride = gridDim.x * blockDim.x;
    for (int k = i; k < nwords; k += stride) p[k] = 0;
}

// ---------------- binning: packed 32B records into 1x1-column lists ----------------

__global__ __launch_bounds__(256) void fill_recs(
    const float* __restrict__ pos, const float* __restrict__ cell,
    const float* __restrict__ emb,
    int* __restrict__ counts, int* __restrict__ ovf_cnt,
    float4* __restrict__ binrec, int* __restrict__ ovf,
    int N, int n)
{
    int i = blockIdx.x * blockDim.x + threadIdx.x;
    if (i >= N) return;
    float inv_sp = inv_spacing(cell, n);
    float px = pos[3 * i + 0] * inv_sp;
    float py = pos[3 * i + 1] * inv_sp;
    float pz = pos[3 * i + 2] * inv_sp;
    int cx = (int)rintf(px); if (cx >= n) cx -= n; else if (cx < 0) cx += n;
    int cy = (int)rintf(py); if (cy >= n) cy -= n; else if (cy < 0) cy += n;
    int bin = cx * n + cy;
    int slot = atomicAdd(&counts[bin], 1);
    if (slot < KColCAP) {
        const float4* e4 = (const float4*)(emb + (size_t)i * 8);
        float4 e0 = e4[0], e1 = e4[1];
        __half2 h01 = __floats2half2_rn(e0.x, e0.y);
        __half2 h23 = __floats2half2_rn(e0.z, e0.w);
        __half2 h45 = __floats2half2_rn(e1.x, e1.y);
        __half2 h67 = __floats2half2_rn(e1.z, e1.w);
        unsigned int u01 = *(unsigned int*)&h01;
        unsigned int u23 = *(unsigned int*)&h23;
        unsigned int u45 = *(unsigned int*)&h45;
        unsigned int u67 = *(unsigned int*)&h67;
        float4* r = binrec + (size_t)(bin * KColCAP + slot) * 2;
        r[0] = make_float4(px, py, pz, __uint_as_float(u01));
        r[1] = make_float4(__uint_as_float(u23), __uint_as_float(u45),
                           __uint_as_float(u67), 0.0f);
    } else {
        int o = atomicAdd(ovf_cnt, 1);
        ovf[o] = i;   // ovf sized N: cannot overflow
    }
}

// ---------------- wave-scatter gather: persistent-lite ----------------
// Each block processes tpb contiguous column-group tiles; wave wv handles
// column (x, ygrp*4+wv). LDS: per-wave private [8ch][n]. No barriers.

__global__ __launch_bounds__(256) void gather_scatter(
    const float4* __restrict__ binrec, const int* __restrict__ counts,
    float* __restrict__ out, int n, int nzc, int tpb)
{
    extern __shared__ float lds[];
    const int tid = threadIdx.x;
    const int lane = tid & 63;
    const int wv = tid >> 6;
    const int nb = nzc * n;
    const size_t n3 = (size_t)n * n * n;

    float* col = lds + wv * 8 * n;     // [8][n] private to this wave

    int t0 = blockIdx.x * tpb;
    int t1 = t0 + tpb; if (t1 > nb) t1 = nb;

    for (int t = t0; t < t1; ++t) {
        const int x = t / nzc;
        const int ygrp = t - x * nzc;
        const int y = ygrp * 4 + wv;

        // zero this wave's column (8n floats = 2n float4)
        {
            nfloat4* c4 = (nfloat4*)col;
            const int z4 = 2 * n;
            for (int i = lane; i < z4; i += 64)
                c4[i] = (nfloat4)(0.f);
        }

        // 9 neighbor-bin meta in registers (wave-uniform broadcast loads)
        int base[9], pref[10];
        pref[0] = 0;
        #pragma unroll
        for (int j = 0; j < 9; ++j) {
            int jx = j / 3, jy = j - 3 * (j / 3);
            int xb = x + jx - 1; if (xb < 0) xb += n; else if (xb >= n) xb -= n;
            int yb = y + jy - 1; if (yb < 0) yb += n; else if (yb >= n) yb -= n;
            int bin = xb * n + yb;
            base[j] = bin * KColCAP;
            int c = counts[bin];
            c = (c < KColCAP) ? c : KColCAP;
            pref[j + 1] = pref[j] + c;
        }
        const int tot = pref[9];

        // lane = (atom slot s, z-corner zc)
        const int s  = lane / 3;           // 0..21 (lane 63 inactive)
        const int zc = lane - 3 * s - 1;   // -1, 0, +1

        for (int q0 = 0; q0 < tot; q0 += 21) {
            const int qq = q0 + s;
            if (s < 21 && qq < tot) {
                int rec = base[0] + qq;
                int jxv = 0, jyv = 0;
                #pragma unroll
                for (int k = 1; k < 9; ++k) {
                    bool ge = (qq >= pref[k]);
                    int cand = base[k] + (qq - pref[k]);
                    rec = ge ? cand : rec;
                    jxv = ge ? (k / 3) : jxv;
                    jyv = ge ? (k - 3 * (k / 3)) : jyv;
                }
                float4 a0 = binrec[2 * (size_t)rec];
                float4 a1 = binrec[2 * (size_t)rec + 1];

                float cxf = rintf(a0.x); float dx = a0.x - cxf;
                float cyf = rintf(a0.y); float dy = a0.y - cyf;
                float czf = rintf(a0.z); float dz = a0.z - czf;

                float tx = 0.5f + (float)(1 - jxv) * dx;
                float wx = (jxv == 1) ? (0.75f - dx * dx) : (0.5f * tx * tx);
                float ty = 0.5f + (float)(1 - jyv) * dy;
                float wy = (jyv == 1) ? (0.75f - dy * dy) : (0.5f * ty * ty);
                float tz = 0.5f + (float)zc * dz;
                float wz = (zc == 0) ? (0.75f - dz * dz) : (0.5f * tz * tz);
                float w = wx * wy * wz;

                float2 e01 = unpack_h2(a0.w);
                float2 e23 = unpack_h2(a1.x);
                float2 e45 = unpack_h2(a1.y);
                float2 e67 = unpack_h2(a1.z);

                int cz = (int)czf; if (cz >= n) cz -= n; else if (cz < 0) cz += n;
                int z = cz + zc; if (z < 0) z += n; else if (z >= n) z -= n;

                float* p = col + z;                   // ch stride n
                atomicAdd(p + 0 * n, w * e01.x);
                atomicAdd(p + 1 * n, w * e01.y);
                atomicAdd(p + 2 * n, w * e23.x);
                atomicAdd(p + 3 * n, w * e23.y);
                atomicAdd(p + 4 * n, w * e45.x);
                atomicAdd(p + 5 * n, w * e45.y);
                atomicAdd(p + 6 * n, w * e67.x);
                atomicAdd(p + 7 * n, w * e67.y);
            }
        }
        // No barrier: column is wave-private; DS ops are in-order per wave.

        // writeout: per channel one PLAIN float4 per lane (z = 4*lane..+3)
        const int z0 = lane * 4;
        if (z0 < n) {
            const size_t colbase = ((size_t)x * n + y) * (size_t)n + z0;
            #pragma unroll
            for (int ch = 0; ch < 8; ++ch) {
                nfloat4 v = *(const nfloat4*)(col + ch * n + z0);
                *(nfloat4*)(out + (size_t)ch * n3 + colbase) = v;
            }
        }
    }
}

// overflow cleanup: global planar atomics for atoms that missed their bin list
__global__ __launch_bounds__(256) void deposit_overflow(
    const float* __restrict__ pos, const float* __restrict__ cell,
    const float* __restrict__ emb, const int* __restrict__ ovf_cnt,
    const int* __restrict__ ovf, float* __restrict__ out, int n)
{
    int m = *ovf_cnt;
    int i = blockIdx.x * blockDim.x + threadIdx.x;
    if (i >= m) return;
    int ai = ovf[i];
    float inv_sp = inv_spacing(cell, n);
    float p[3], d[3]; int c0[3];
    #pragma unroll
    for (int kk = 0; kk < 3; ++kk) {
        p[kk] = pos[3 * ai + kk] * inv_sp;
        c0[kk] = (int)rintf(p[kk]);
        d[kk] = p[kk] - (float)c0[kk];
    }
    float w[3][3];
    #pragma unroll
    for (int kk = 0; kk < 3; ++kk) {
        float dd = d[kk];
        w[kk][0] = tsc_w(-1, dd); w[kk][1] = tsc_w(0, dd); w[kk][2] = tsc_w(1, dd);
    }
    int W[3][3];
    #pragma unroll
    for (int kk = 0; kk < 3; ++kk)
        #pragma unroll
        for (int a = 0; a < 3; ++a) {
            int v = c0[kk] - 1 + a; if (v < 0) v += n; else if (v >= n) v -= n;
            W[kk][a] = v;
        }
    size_t n3 = (size_t)n * n * n;
    const float4* e4 = (const float4*)(emb + (size_t)ai * 8);
    float4 e0 = e4[0], e1 = e4[1];
    float e[8] = {e0.x, e0.y, e0.z, e0.w, e1.x, e1.y, e1.z, e1.w};
    for (int a = 0; a < 3; ++a)
        for (int bq = 0; bq < 3; ++bq)
            for (int cq = 0; cq < 3; ++cq) {
                float wt = w[0][a] * w[1][bq] * w[2][cq];
                size_t g = ((size_t)W[0][a] * n + W[1][bq]) * n + W[2][cq];
                #pragma unroll
                for (int ch = 0; ch < 8; ++ch)
                    atomicAdd(out + (size_t)ch * n3 + g, wt * e[ch]);
            }
}

// ---------------- fallback: interleaved atomics + transpose ----------------

__global__ __launch_bounds__(256) void deposit_tsc8_ilv(
    const float* __restrict__ pos,
    const float* __restrict__ cell,
    const float* __restrict__ emb,
    float* __restrict__ ws,
    int total, int n)
{
    int t = blockIdx.x * blockDim.x + threadIdx.x;
    if (t >= total) return;
    int atom = t / 27;
    int c    = t - atom * 27;
    int a    = c / 9;
    int rem  = c - a * 9;
    int b    = rem / 3;
    int cc   = rem - b * 3;

    float inv_sp = inv_spacing(cell, n);

    float px = pos[3 * atom + 0] * inv_sp;
    float py = pos[3 * atom + 1] * inv_sp;
    float pz = pos[3 * atom + 2] * inv_sp;

    int cx = (int)rintf(px);  float dx = px - (float)cx;
    int cy = (int)rintf(py);  float dy = py - (float)cy;
    int cz = (int)rintf(pz);  float dz = pz - (float)cz;

    float w = tsc_w(a - 1, dx) * tsc_w(b - 1, dy) * tsc_w(cc - 1, dz);

    int x = cx - 1 + a;  if (x < 0) x += n; else if (x >= n) x -= n;
    int y = cy - 1 + b;  if (y < 0) y += n; else if (y >= n) y -= n;
    int z = cz - 1 + cc; if (z < 0) z += n; else if (z >= n) z -= n;

    const float4* e4 = (const float4*)(emb + (size_t)atom * 8);
    float4 e0 = e4[0], e1 = e4[1];

    float* p = ws + ((size_t)((x * n + y) * n + z)) * 8;
    atomicAdd(p + 0, w * e0.x);
    atomicAdd(p + 1, w * e0.y);
    atomicAdd(p + 2, w * e0.z);
    atomicAdd(p + 3, w * e0.w);
    atomicAdd(p + 4, w * e1.x);
    atomicAdd(p + 5, w * e1.y);
    atomicAdd(p + 6, w * e1.z);
    atomicAdd(p + 7, w * e1.w);
}

__global__ __launch_bounds__(256) void transpose_ilv8(
    const float* __restrict__ ws, float* __restrict__ out, int n3)
{
    int t = blockIdx.x * blockDim.x + threadIdx.x;
    int g0 = t * 4;
    if (g0 >= n3) return;
    const float4* w4 = (const float4*)(ws + (size_t)g0 * 8);
    float4 r0 = w4[0], r1 = w4[1];
    float4 r2 = w4[2], r3 = w4[3];
    float4 r4 = w4[4], r5 = w4[5];
    float4 r6 = w4[6], r7 = w4[7];

    *(float4*)(out + (size_t)0 * n3 + g0) = make_float4(r0.x, r2.x, r4.x, r6.x);
    *(float4*)(out + (size_t)1 * n3 + g0) = make_float4(r0.y, r2.y, r4.y, r6.y);
    *(float4*)(out + (size_t)2 * n3 + g0) = make_float4(r0.z, r2.z, r4.z, r6.z);
    *(float4*)(out + (size_t)3 * n3 + g0) = make_float4(r0.w, r2.w, r4.w, r6.w);
    *(float4*)(out + (size_t)4 * n3 + g0) = make_float4(r1.x, r3.x, r5.x, r7.x);
    *(float4*)(out + (size_t)5 * n3 + g0) = make_float4(r1.y, r3.y, r5.y, r7.y);
    *(float4*)(out + (size_t)6 * n3 + g0) = make_float4(r1.z, r3.z, r5.z, r7.z);
    *(float4*)(out + (size_t)7 * n3 + g0) = make_float4(r1.w, r3.w, r5.w, r7.w);
}

// ---------------- fallback: generic planar atomics ----------------

__global__ __launch_bounds__(256) void deposit_tsc_gen(
    const float* __restrict__ pos,
    const float* __restrict__ cell,
    const float* __restrict__ emb,
    float* __restrict__ out,
    int N, int n, int C)
{
    int i = blockIdx.x * blockDim.x + threadIdx.x;
    if (i >= N) return;

    float inv_sp = inv_spacing(cell, n);

    float p[3], d[3];
    int c0[3];
    #pragma unroll
    for (int k = 0; k < 3; ++k) {
        p[k] = pos[3 * i + k] * inv_sp;
        c0[k] = (int)rintf(p[k]);
        d[k] = p[k] - (float)c0[k];
    }
    float w[3][3];
    #pragma unroll
    for (int k = 0; k < 3; ++k) {
        float dd = d[k], d2 = dd * dd;
        w[k][0] = 0.125f * (1.0f - 4.0f * dd + 4.0f * d2);
        w[k][1] = 0.25f  * (3.0f - 4.0f * d2);
        w[k][2] = 0.125f * (1.0f + 4.0f * dd + 4.0f * d2);
    }
    int W[3][3];
    #pragma unroll
    for (int k = 0; k < 3; ++k) {
        #pragma unroll
        for (int a = 0; a < 3; ++a) {
            int v = c0[k] - 1 + a; if (v < 0) v += n; else if (v >= n) v -= n;
            W[k][a] = v;
        }
    }
    int n3 = n * n * n;
    for (int a = 0; a < 3; ++a)
        for (int b = 0; b < 3; ++b)
            for (int cc = 0; cc < 3; ++cc) {
                float wt = w[0][a] * w[1][b] * w[2][cc];
                int g = (W[0][a] * n + W[1][b]) * n + W[2][cc];
                for (int ch = 0; ch < C; ++ch)
                    atomicAdd(out + (size_t)ch * n3 + g, wt * emb[(size_t)i * C + ch]);
            }
}

extern "C" void kernel_launch(void* const* d_in, const int* in_sizes, int n_in,
                              void* d_out, int out_size, void* d_ws, size_t ws_size,
                              hipStream_t stream) {
    const float* pos  = (const float*)d_in[0];
    const float* cell = (const float*)d_in[1];
    const float* emb  = (const float*)d_in[2];
    float* out = (float*)d_out;
    float* ws  = (float*)d_ws;

    int N = in_sizes[0] / 3;
    int C = in_sizes[2] / N;
    long long n3l = (long long)out_size / C;
    int n = (int)llroundf(cbrtf((float)n3l));
    int n3 = (int)n3l;

    int block = 256;

    // ---- wave-scatter fast path ----
    {
        int nb = n * n;
        size_t lds_bytes = (size_t)4 * 8 * n * sizeof(float);   // 128n B
        size_t rec_off = (((size_t)nb + 4 + (size_t)N) * sizeof(int) + 15) & ~(size_t)15;
        size_t need = rec_off + (size_t)nb * KColCAP * 32;
        bool ok = (C == 8) && (n % 4 == 0) && n >= 8 && n <= 256
                  && lds_bytes <= 64 * 1024
                  && ws_size >= need
                  && ((long long)n * n * n == n3l);
        if (ok) {
            int* counts  = (int*)d_ws;
            int* ovf_cnt = counts + nb;
            int* ovf     = counts + nb + 4;
            float4* binrec = (float4*)((char*)d_ws + rec_off);

            // own zero kernel instead of hipMemsetAsync (suspect ~147us fill)
            zero_ints<<<256, block, 0, stream>>>(counts, nb + 4);
            fill_recs<<<(N + block - 1) / block, block, 0, stream>>>(
                pos, cell, emb, counts, ovf_cnt, binrec, ovf, N, n);

            int nzc = n / 4;
            int nbt = nzc * n;
            int nblocks = 2500;
            if (nblocks > nbt) nblocks = nbt;
            int tpb = (nbt + nblocks - 1) / nblocks;
            gather_scatter<<<nblocks, block, lds_bytes, stream>>>(
                binrec, counts, out, n, nzc, tpb);

            deposit_overflow<<<(N + block - 1) / block, block, 0, stream>>>(
                pos, cell, emb, ovf_cnt, ovf, out, n);
            return;
        }
    }

    // ---- fallback: interleaved atomics + transpose ----
    size_t need = (size_t)out_size * sizeof(float);
    if (C == 8 && ws_size >= need && (n3 % 4) == 0) {
        (void)hipMemsetAsync(d_ws, 0, need, stream);
        int total = N * 27;
        deposit_tsc8_ilv<<<(total + block - 1) / block, block, 0, stream>>>(
            pos, cell, emb, ws, total, n);
        int tthreads = n3 / 4;
        transpose_ilv8<<<(tthreads + block - 1) / block, block, 0, stream>>>(
            ws, out, n3);
    } else {
        (void)hipMemsetAsync(d_out, 0, (size_t)out_size * sizeof(float), stream);
        int grid = (N + block - 1) / block;
        deposit_tsc_gen<<<grid, block, 0, stream>>>(pos, cell, emb, out, N, n, C);
    }
}